// Round 3
// baseline (290.339 us; speedup 1.0000x reference)
//
#include <hip/hip_runtime.h>
#include <hip/hip_bf16.h>
#include <stdint.h>

// Conv2d: x[128][256][256] f32, w[256][128][3][3] f32, bias[256] f32 ->
// out[256][256][256] f32. pad=1 stride=1.  bf16 MFMA implicit GEMM.
// R3: waves share m (A-frags deduped via L1), n-tile=256 (full row),
//     register-prefetch double-buffered x staging, LDS-free preps.
//   ws: x_p bf16 [258][258][128] = 17,040,384 B ; W_pk bf16 [9][256][128]

#define CIN   128
#define COUT  256
#define HH    256
#define WW    256
#define WP    258
#define XP_ELEMS (258 * 258 * 128)   // 8,520,192 bf16 elements

typedef __attribute__((ext_vector_type(8))) __bf16 bf16x8;
typedef __attribute__((ext_vector_type(4))) float  floatx4;

// ---------------- prep 1: zero the padded border (vectorized) ----------------
// 1028 border pixels x 16 icg-chunks of 16B = 16,448 uint4 stores
__global__ __launch_bounds__(256) void zero_border(unsigned short* __restrict__ xp) {
    int id = blockIdx.x * 256 + threadIdx.x;
    if (id >= 1028 * 16) return;
    int p = id >> 4, icg = id & 15;
    int hp, wp;
    if (p < 258)      { hp = 0;   wp = p; }
    else if (p < 516) { hp = 257; wp = p - 258; }
    else { int s = p - 516; hp = 1 + (s >> 1); wp = (s & 1) * 257; }
    uint4 z = {0u, 0u, 0u, 0u};
    *(uint4*)(xp + ((size_t)hp * WP + wp) * CIN + icg * 8) = z;
}

// ---------------- prep 2: transpose+cast, no LDS ----------------
// thread owns (h, w, icg): gathers 8 channels (each 64B line fully used by the
// 16 wq-lanes of the block's waves), stores one 16B chunk of xp.
__global__ __launch_bounds__(256) void xpose_pad(const float* __restrict__ x,
                                                 unsigned short* __restrict__ xp) {
    int h  = blockIdx.x;             // 0..255
    int w0 = blockIdx.y << 4;        // 16-col strips
    int wq  = threadIdx.x & 15;
    int icg = threadIdx.x >> 4;      // 0..15
    const float* src = x + (size_t)(icg * 8) * (HH * WW) + h * WW + w0 + wq;
    union { unsigned short s[8]; uint4 v; } u;
#pragma unroll
    for (int j = 0; j < 8; ++j) {
        __hip_bfloat16 b = __float2bfloat16(src[(size_t)j * (HH * WW)]);
        u.s[j] = __builtin_bit_cast(unsigned short, b);
    }
    *(uint4*)(xp + ((size_t)(h + 1) * WP + (w0 + wq + 1)) * CIN + icg * 8) = u.v;
}

// ---------------- prep 3: pack weights -> bf16 W_pk[kk][o][ic], coalesced ----------------
__global__ __launch_bounds__(256) void wpack(const float* __restrict__ w,
                                             unsigned short* __restrict__ wp) {
    int rem = blockIdx.x * 256 + threadIdx.x;   // o*128+ic, 0..32767
    const float* src = w + (size_t)rem * 9;
#pragma unroll
    for (int kk = 0; kk < 9; ++kk) {
        __hip_bfloat16 b = __float2bfloat16(src[kk]);
        wp[(size_t)kk * (COUT * CIN) + rem] = __builtin_bit_cast(unsigned short, b);
    }
}

// ---------------- main conv ----------------
// block = 512 thr (8 waves), tile 128m x 256n (n = full row h). waves share m.
// LDS x tile: [r=3][c=258][32ch] bf16 = 49,536 B, staged as 3096 16B chunks.
// K-loop: 4 x (32 ch); per kk: 8 shared A-frags (global, L1-dedup) + 2 B-frags
// (LDS) + 16 MFMA.  x staging register-prefetched one iter ahead.
__global__ __launch_bounds__(512, 2) void conv_mfma(
    const unsigned short* __restrict__ xp,   // [258][258][128] bf16
    const unsigned short* __restrict__ wpk,  // [9][256][128]   bf16
    const float* __restrict__ bias,          // [256] f32
    float* __restrict__ out) {               // [256][65536] f32
    __shared__ __align__(16) unsigned short x_lds[3 * 258 * 32];  // 49,536 B

    const int tid  = threadIdx.x;
    const int lane = tid & 63;
    const int wv   = tid >> 6;          // 0..7
    const int l15  = lane & 15;
    const int lg   = lane >> 4;         // 0..3
    const int h  = blockIdx.x;          // row = n-tile
    const int m0 = blockIdx.y << 7;     // 0 or 128

    // decode staging chunks: id = (r*258+c)*4 + icg ; 6 full rounds + 24 rem
    int goff[6];
#pragma unroll
    for (int k = 0; k < 6; ++k) {
        int id = tid + k * 512;
        int icg = id & 3, cidx = id >> 2;
        int r = cidx / 258, c = cidx - r * 258;
        goff[k] = ((h + r) * WP + c) * CIN + icg * 8;
    }
    const bool hrem = tid < 24;
    int grem = 0;
    if (hrem) {
        int id = 3072 + tid;
        int icg = id & 3, cidx = id >> 2;
        int r = cidx / 258, c = cidx - r * 258;
        grem = ((h + r) * WP + c) * CIN + icg * 8;
    }

    uint4 pf[6], pfr;
#pragma unroll
    for (int k = 0; k < 6; ++k) pf[k] = *(const uint4*)(xp + goff[k]);
    if (hrem) pfr = *(const uint4*)(xp + grem);

    floatx4 acc[8][2];
#pragma unroll
    for (int fi = 0; fi < 8; ++fi)
#pragma unroll
        for (int fj = 0; fj < 2; ++fj) {
            floatx4 z = {0.f, 0.f, 0.f, 0.f};
            acc[fi][fj] = z;
        }

    for (int ic0 = 0; ic0 < CIN; ic0 += 32) {
        if (ic0) __syncthreads();           // prior iter's ds_reads complete
#pragma unroll
        for (int k = 0; k < 6; ++k)
            *(uint4*)(x_lds + (size_t)(tid + k * 512) * 8) = pf[k];
        if (hrem) *(uint4*)(x_lds + (size_t)(3072 + tid) * 8) = pfr;
        __syncthreads();
        if (ic0 < 96) {                     // prefetch next K-block during compute
#pragma unroll
            for (int k = 0; k < 6; ++k)
                pf[k] = *(const uint4*)(xp + goff[k] + ic0 + 32);
            if (hrem) pfr = *(const uint4*)(xp + grem + ic0 + 32);
        }

        const unsigned short* wb = wpk + (size_t)(m0 + l15) * CIN + ic0 + lg * 8;
#pragma unroll
        for (int kh = 0; kh < 3; ++kh) {
#pragma unroll
            for (int kw = 0; kw < 3; ++kw) {
                const int kk = kh * 3 + kw;
                bf16x8 b[2];
#pragma unroll
                for (int fj = 0; fj < 2; ++fj) {
                    int c = wv * 32 + fj * 16 + l15 + kw;
                    b[fj] = *(const bf16x8*)(x_lds + ((kh * WP + c) * 32 + lg * 8));
                }
#pragma unroll
                for (int fi = 0; fi < 8; ++fi) {
                    bf16x8 a = *(const bf16x8*)(wb + ((size_t)kk * COUT + fi * 16) * CIN);
                    acc[fi][0] = __builtin_amdgcn_mfma_f32_16x16x32_bf16(a, b[0], acc[fi][0], 0, 0, 0);
                    acc[fi][1] = __builtin_amdgcn_mfma_f32_16x16x32_bf16(a, b[1], acc[fi][1], 0, 0, 0);
                }
            }
        }
    }

    // epilogue: D col=lane&15, row=(lane>>4)*4+reg
    const int nb = h * WW + wv * 32 + l15;
#pragma unroll
    for (int fi = 0; fi < 8; ++fi) {
        int row0 = m0 + fi * 16 + lg * 4;
#pragma unroll
        for (int r = 0; r < 4; ++r) {
            float bv = bias[row0 + r];
            out[(size_t)(row0 + r) * (HH * WW) + nb]      = acc[fi][0][r] + bv;
            out[(size_t)(row0 + r) * (HH * WW) + nb + 16] = acc[fi][1][r] + bv;
        }
    }
}

extern "C" void kernel_launch(void* const* d_in, const int* in_sizes, int n_in,
                              void* d_out, int out_size, void* d_ws, size_t ws_size,
                              hipStream_t stream) {
    (void)in_sizes; (void)n_in; (void)out_size; (void)ws_size;
    const float* x    = (const float*)d_in[0];
    const float* w    = (const float*)d_in[1];
    const float* bias = (const float*)d_in[2];
    float* out = (float*)d_out;

    unsigned short* xp  = (unsigned short*)d_ws;
    unsigned short* wpk = xp + XP_ELEMS;

    zero_border<<<dim3(65), dim3(256), 0, stream>>>(xp);
    xpose_pad<<<dim3(256, 16), dim3(256), 0, stream>>>(x, xp);
    wpack<<<dim3(128), dim3(256), 0, stream>>>(w, wpk);
    conv_mfma<<<dim3(256, 2), dim3(512), 0, stream>>>(xp, wpk, bias, out);
}

// Round 4
// 228.040 us; speedup vs baseline: 1.2732x; 1.2732x over previous
//
#include <hip/hip_runtime.h>
#include <hip/hip_bf16.h>
#include <stdint.h>

// Conv2d: x[128][256][256] f32, w[256][128][3][3] f32, bias[256] f32 ->
// out[256][256][256] f32. pad=1 stride=1.  bf16 MFMA implicit GEMM.
// R4: NO LDS, NO barriers in the conv kernel. With xp channel-innermost,
// a B-fragment is directly a coalesced global 16B/lane load (L2/L3-resident
// xp), and A-fragments are L1-shared weight reads. Pure load<->MFMA loop
// lets the compiler software-pipeline with fine vmcnt (no s_barrier drain —
// the structural stall of R2/R3).
//   ws: x_p bf16 [258][258][128] = 17,040,384 B ; W_pk bf16 [9][256][128]

#define CIN   128
#define COUT  256
#define HH    256
#define WW    256
#define WP    258
#define XP_ELEMS (258 * 258 * 128)

typedef __attribute__((ext_vector_type(8))) __bf16 bf16x8;
typedef __attribute__((ext_vector_type(4))) float  floatx4;

// ---------------- prep 1: zero the padded border (vectorized) ----------------
__global__ __launch_bounds__(256) void zero_border(unsigned short* __restrict__ xp) {
    int id = blockIdx.x * 256 + threadIdx.x;
    if (id >= 1028 * 16) return;
    int p = id >> 4, icg = id & 15;
    int hp, wp;
    if (p < 258)      { hp = 0;   wp = p; }
    else if (p < 516) { hp = 257; wp = p - 258; }
    else { int s = p - 516; hp = 1 + (s >> 1); wp = (s & 1) * 257; }
    uint4 z = {0u, 0u, 0u, 0u};
    *(uint4*)(xp + ((size_t)hp * WP + wp) * CIN + icg * 8) = z;
}

// ---------------- prep 2: transpose+cast x[c][h][w] -> xp[h+1][w+1][c] ----------------
__global__ __launch_bounds__(256) void xpose_pad(const float* __restrict__ x,
                                                 unsigned short* __restrict__ xp) {
    int h  = blockIdx.x;
    int w0 = blockIdx.y << 4;
    int wq  = threadIdx.x & 15;
    int icg = threadIdx.x >> 4;
    const float* src = x + (size_t)(icg * 8) * (HH * WW) + h * WW + w0 + wq;
    union { unsigned short s[8]; uint4 v; } u;
#pragma unroll
    for (int j = 0; j < 8; ++j) {
        __hip_bfloat16 b = __float2bfloat16(src[(size_t)j * (HH * WW)]);
        u.s[j] = __builtin_bit_cast(unsigned short, b);
    }
    *(uint4*)(xp + ((size_t)(h + 1) * WP + (w0 + wq + 1)) * CIN + icg * 8) = u.v;
}

// ---------------- prep 3: pack weights -> bf16 W_pk[kk][o][ic] ----------------
__global__ __launch_bounds__(256) void wpack(const float* __restrict__ w,
                                             unsigned short* __restrict__ wp) {
    int rem = blockIdx.x * 256 + threadIdx.x;   // o*128+ic
    const float* src = w + (size_t)rem * 9;
#pragma unroll
    for (int kk = 0; kk < 9; ++kk) {
        __hip_bfloat16 b = __float2bfloat16(src[kk]);
        wp[(size_t)kk * (COUT * CIN) + rem] = __builtin_bit_cast(unsigned short, b);
    }
}

// ---------------- main conv: barrier-free, LDS-free ----------------
// block = 256 thr (4 waves), tile 128m x 128n. wave tile 64m x 64n.
// Per (ic0,kh,kw): 4 A-frag loads (wpk, L1-shared) + 4 B-frag loads (xp,
// coalesced 16B/lane) + 16 MFMA. No __syncthreads anywhere.
__global__ __launch_bounds__(256, 3) void conv_mfma(
    const unsigned short* __restrict__ xp,   // [258][258][128] bf16
    const unsigned short* __restrict__ wpk,  // [9][256][128]   bf16
    const float* __restrict__ bias,          // [256] f32
    float* __restrict__ out) {               // [256][65536] f32
    const int tid  = threadIdx.x;
    const int lane = tid & 63;
    const int wv   = tid >> 6;          // 0..3
    const int l15  = lane & 15;
    const int lg   = lane >> 4;         // 0..3
    const int h  = blockIdx.x >> 1;
    const int w0 = (blockIdx.x & 1) << 7;
    const int m0 = blockIdx.y << 7;
    const int wave_m = (wv >> 1) << 6;  // 0 or 64
    const int wave_n = (wv & 1) << 6;   // 0 or 64

    // B base: pixel (h+kh, w0+wave_n+l15+kw+fj*16), channels ic0+lg*8..+8
    const unsigned short* bbase =
        xp + ((size_t)h * WP + w0 + wave_n + l15) * CIN + lg * 8;
    // A base: row m0+wave_m+l15+fi*16, channels ic0+lg*8..+8, tap kk
    const unsigned short* abase =
        wpk + (size_t)(m0 + wave_m + l15) * CIN + lg * 8;

    floatx4 acc[4][4];
#pragma unroll
    for (int fi = 0; fi < 4; ++fi)
#pragma unroll
        for (int fj = 0; fj < 4; ++fj) {
            floatx4 z = {0.f, 0.f, 0.f, 0.f};
            acc[fi][fj] = z;
        }

    for (int ic0 = 0; ic0 < CIN; ic0 += 32) {
#pragma unroll
        for (int kh = 0; kh < 3; ++kh) {
#pragma unroll
            for (int kw = 0; kw < 3; ++kw) {
                const int kk = kh * 3 + kw;
                bf16x8 a[4], b[4];
#pragma unroll
                for (int fj = 0; fj < 4; ++fj)
                    b[fj] = *(const bf16x8*)(bbase + ic0 +
                        ((size_t)kh * WP + kw + fj * 16) * CIN);
#pragma unroll
                for (int fi = 0; fi < 4; ++fi)
                    a[fi] = *(const bf16x8*)(abase + ic0 +
                        ((size_t)kk * COUT + fi * 16) * CIN);
#pragma unroll
                for (int fi = 0; fi < 4; ++fi)
#pragma unroll
                    for (int fj = 0; fj < 4; ++fj)
                        acc[fi][fj] = __builtin_amdgcn_mfma_f32_16x16x32_bf16(
                            a[fi], b[fj], acc[fi][fj], 0, 0, 0);
            }
        }
    }

    // epilogue: D col=lane&15, row=(lane>>4)*4+reg  (R2-proven, WRITE clean)
    const int nb = h * WW + w0 + wave_n + l15;
#pragma unroll
    for (int fi = 0; fi < 4; ++fi) {
        int row0 = m0 + wave_m + fi * 16 + lg * 4;
#pragma unroll
        for (int r = 0; r < 4; ++r) {
            float bv = bias[row0 + r];
#pragma unroll
            for (int fj = 0; fj < 4; ++fj)
                out[(size_t)(row0 + r) * (HH * WW) + nb + fj * 16] = acc[fi][fj][r] + bv;
        }
    }
}

extern "C" void kernel_launch(void* const* d_in, const int* in_sizes, int n_in,
                              void* d_out, int out_size, void* d_ws, size_t ws_size,
                              hipStream_t stream) {
    (void)in_sizes; (void)n_in; (void)out_size; (void)ws_size;
    const float* x    = (const float*)d_in[0];
    const float* w    = (const float*)d_in[1];
    const float* bias = (const float*)d_in[2];
    float* out = (float*)d_out;

    unsigned short* xp  = (unsigned short*)d_ws;
    unsigned short* wpk = xp + XP_ELEMS;

    zero_border<<<dim3(65), dim3(256), 0, stream>>>(xp);
    xpose_pad<<<dim3(256, 16), dim3(256), 0, stream>>>(x, xp);
    wpack<<<dim3(128), dim3(256), 0, stream>>>(w, wpk);
    conv_mfma<<<dim3(512, 2), dim3(256), 0, stream>>>(xp, wpk, bias, out);
}

// Round 5
// 205.907 us; speedup vs baseline: 1.4100x; 1.1075x over previous
//
#include <hip/hip_runtime.h>
#include <hip/hip_bf16.h>
#include <stdint.h>

// Conv2d: x[128][256][256] f32, w[256][128][3][3] f32, bias[256] f32 ->
// out[256][256][256] f32. pad=1 stride=1. bf16 MFMA implicit GEMM.
// R5 = R2 structure + (a) full-wave global_load_lds width=16 staging,
// (b) LDS double-buffer with DMA issued across the compute phase,
// (c) swizzled LDS layout (coalesced DMA + conflict-free ds_read_b128),
// (d) A-fragments software-pipelined 2 taps ahead in registers.
//   ws: x_p bf16 [258][258][128] = 17,040,384 B ; W_pk bf16 [9][256][128]

#define CIN   128
#define COUT  256
#define HH    256
#define WW    256
#define WP    258
#define XP_ELEMS (258 * 258 * 128)

// per-buffer: 3 rows x 130 cols x 4 slots = 1560 chunks (+40 slack) of 16B
#define CHUNKS      1560
#define BUF_CHUNKS  1600
#define BUF_ELEMS   (BUF_CHUNKS * 8)    // shorts

typedef __attribute__((ext_vector_type(8))) __bf16 bf16x8;
typedef __attribute__((ext_vector_type(4))) float  floatx4;

// ---------------- prep 1: zero the padded border (vectorized) ----------------
__global__ __launch_bounds__(256) void zero_border(unsigned short* __restrict__ xp) {
    int id = blockIdx.x * 256 + threadIdx.x;
    if (id >= 1028 * 16) return;
    int p = id >> 4, icg = id & 15;
    int hp, wp;
    if (p < 258)      { hp = 0;   wp = p; }
    else if (p < 516) { hp = 257; wp = p - 258; }
    else { int s = p - 516; hp = 1 + (s >> 1); wp = (s & 1) * 257; }
    uint4 z = {0u, 0u, 0u, 0u};
    *(uint4*)(xp + ((size_t)hp * WP + wp) * CIN + icg * 8) = z;
}

// ---------------- prep 2: transpose+cast x[c][h][w] -> xp[h+1][w+1][c] ----------------
__global__ __launch_bounds__(256) void xpose_pad(const float* __restrict__ x,
                                                 unsigned short* __restrict__ xp) {
    int h  = blockIdx.x;
    int w0 = blockIdx.y << 4;
    int wq  = threadIdx.x & 15;
    int icg = threadIdx.x >> 4;
    const float* src = x + (size_t)(icg * 8) * (HH * WW) + h * WW + w0 + wq;
    union { unsigned short s[8]; uint4 v; } u;
#pragma unroll
    for (int j = 0; j < 8; ++j) {
        __hip_bfloat16 b = __float2bfloat16(src[(size_t)j * (HH * WW)]);
        u.s[j] = __builtin_bit_cast(unsigned short, b);
    }
    *(uint4*)(xp + ((size_t)(h + 1) * WP + (w0 + wq + 1)) * CIN + icg * 8) = u.v;
}

// ---------------- prep 3: pack weights -> bf16 W_pk[kk][o][ic] ----------------
__global__ __launch_bounds__(256) void wpack(const float* __restrict__ w,
                                             unsigned short* __restrict__ wp) {
    int rem = blockIdx.x * 256 + threadIdx.x;   // o*128+ic
    const float* src = w + (size_t)rem * 9;
#pragma unroll
    for (int kk = 0; kk < 9; ++kk) {
        __hip_bfloat16 b = __float2bfloat16(src[kk]);
        wp[(size_t)kk * (COUT * CIN) + rem] = __builtin_bit_cast(unsigned short, b);
    }
}

// ---------------- async global->LDS, width 16 (m97 idiom) ----------------
__device__ inline void dma16(const unsigned short* g, unsigned short* l) {
    __builtin_amdgcn_global_load_lds(
        (const __attribute__((address_space(1))) unsigned short*)g,
        (__attribute__((address_space(3))) unsigned short*)l, 16, 0, 0);
}

// ---------------- main conv ----------------
// 256 thr (4 waves, 2x2 wave tiles of 64x64), block tile 128m x 128n.
// LDS chunk (r, c, slot): index (r*130+c)*4 + slot, slot holds icg=(slot-(c>>1))&3.
__global__ __launch_bounds__(256, 3) void conv_mfma(
    const unsigned short* __restrict__ xp,   // [258][258][128] bf16
    const unsigned short* __restrict__ wpk,  // [9][256][128]   bf16
    const float* __restrict__ bias,          // [256] f32
    float* __restrict__ out) {               // [256][65536] f32
    __shared__ __align__(16) unsigned short x_lds[2 * BUF_ELEMS];  // 51,200 B

    const int tid  = threadIdx.x;
    const int lane = tid & 63;
    const int wv   = tid >> 6;          // 0..3
    const int l15  = lane & 15;
    const int lg   = lane >> 4;         // 0..3
    const int h  = blockIdx.x >> 1;
    const int w0 = (blockIdx.x & 1) << 7;
    const int m0 = blockIdx.y << 7;
    const int wave_m = (wv >> 1) << 6;
    const int wave_n = (wv & 1) << 6;

    // ---- staging descriptors: 6 full rounds + wave0 remainder ----
    int goff[7];
#pragma unroll
    for (int k = 0; k < 6; ++k) {
        int s = k * 256 + tid;
        int r = s / 520, t = s - r * 520;
        int c = t >> 2, slot = t & 3;
        int icg = (slot - (c >> 1)) & 3;
        goff[k] = ((h + r) * WP + w0 + c) * CIN + icg * 8;
    }
    {
        int s = 1536 + lane; if (s > 1559) s = 1559;   // clamp dup into slack
        int r = s / 520, t = s - r * 520;
        int c = t >> 2, slot = t & 3;
        int icg = (slot - (c >> 1)) & 3;
        goff[6] = ((h + r) * WP + w0 + c) * CIN + icg * 8;
    }

    // ---- B-frag LDS element offsets (per fj,kw), r-term added per tap ----
    int coff[3][4];
#pragma unroll
    for (int kw = 0; kw < 3; ++kw)
#pragma unroll
        for (int fj = 0; fj < 4; ++fj) {
            int c = wave_n + fj * 16 + l15 + kw;
            coff[kw][fj] = (c * 4 + ((lg + (c >> 1)) & 3)) * 8;
        }

    const unsigned short* abase = wpk + (size_t)(m0 + wave_m + l15) * CIN + lg * 8;

    floatx4 acc[4][4];
#pragma unroll
    for (int fi = 0; fi < 4; ++fi)
#pragma unroll
        for (int fj = 0; fj < 4; ++fj) {
            floatx4 z = {0.f, 0.f, 0.f, 0.f};
            acc[fi][fj] = z;
        }

    // ---- prologue: DMA K-block 0 into buf0; A-frags for taps 0,1 ----
#pragma unroll
    for (int k = 0; k < 6; ++k)
        dma16(xp + goff[k], x_lds + (size_t)(k * 256 + tid) * 8);
    if (wv == 0)
        dma16(xp + goff[6], x_lds + (size_t)(1536 + lane) * 8);

    bf16x8 a0[4], a1[4];
#pragma unroll
    for (int fi = 0; fi < 4; ++fi) {
        a0[fi] = *(const bf16x8*)(abase + 0 * 32768 + fi * 2048);
        a1[fi] = *(const bf16x8*)(abase + 1 * 32768 + fi * 2048);
    }

    for (int it = 0; it < 4; ++it) {
        const int ic0 = it * 32;
        __syncthreads();                       // own-DMA drained -> buf[it&1] ready
        const unsigned short* cur = x_lds + (it & 1) * BUF_ELEMS;
        if (it < 3) {                          // DMA next K-block during compute
            unsigned short* nxt = x_lds + ((it + 1) & 1) * BUF_ELEMS;
#pragma unroll
            for (int k = 0; k < 6; ++k)
                dma16(xp + goff[k] + ic0 + 32, nxt + (size_t)(k * 256 + tid) * 8);
            if (wv == 0)
                dma16(xp + goff[6] + ic0 + 32, nxt + (size_t)(1536 + lane) * 8);
        }

#pragma unroll
        for (int kk = 0; kk < 9; ++kk) {
            const int kh = kk / 3, kw = kk - kh * 3;
            // prefetch A for tap kk+2 (wraps into next K-block)
            const int kk2 = kk + 2;
            const int kt  = (kk2 >= 9) ? kk2 - 9 : kk2;
            int icp = (kk2 >= 9) ? ic0 + 32 : ic0;
            if (icp > 96) icp = 96;            // clamped dummy (never consumed)
            bf16x8 an[4];
#pragma unroll
            for (int fi = 0; fi < 4; ++fi)
                an[fi] = *(const bf16x8*)(abase + (size_t)kt * 32768 + fi * 2048 + icp);

            bf16x8 b[4];
#pragma unroll
            for (int fj = 0; fj < 4; ++fj)
                b[fj] = *(const bf16x8*)(cur + kh * 4160 + coff[kw][fj]);

#pragma unroll
            for (int fi = 0; fi < 4; ++fi)
#pragma unroll
                for (int fj = 0; fj < 4; ++fj)
                    acc[fi][fj] = __builtin_amdgcn_mfma_f32_16x16x32_bf16(
                        a0[fi], b[fj], acc[fi][fj], 0, 0, 0);
#pragma unroll
            for (int fi = 0; fi < 4; ++fi) { a0[fi] = a1[fi]; a1[fi] = an[fi]; }
        }
    }

    // epilogue: D col=lane&15, row=(lane>>4)*4+reg (proven R2/R4)
    const int nb = h * WW + w0 + wave_n + l15;
#pragma unroll
    for (int fi = 0; fi < 4; ++fi) {
        int row0 = m0 + wave_m + fi * 16 + lg * 4;
#pragma unroll
        for (int r = 0; r < 4; ++r) {
            float bv = bias[row0 + r];
#pragma unroll
            for (int fj = 0; fj < 4; ++fj)
                out[(size_t)(row0 + r) * (HH * WW) + nb + fj * 16] = acc[fi][fj][r] + bv;
        }
    }
}

extern "C" void kernel_launch(void* const* d_in, const int* in_sizes, int n_in,
                              void* d_out, int out_size, void* d_ws, size_t ws_size,
                              hipStream_t stream) {
    (void)in_sizes; (void)n_in; (void)out_size; (void)ws_size;
    const float* x    = (const float*)d_in[0];
    const float* w    = (const float*)d_in[1];
    const float* bias = (const float*)d_in[2];
    float* out = (float*)d_out;

    unsigned short* xp  = (unsigned short*)d_ws;
    unsigned short* wpk = xp + XP_ELEMS;

    zero_border<<<dim3(65), dim3(256), 0, stream>>>(xp);
    xpose_pad<<<dim3(256, 16), dim3(256), 0, stream>>>(x, xp);
    wpack<<<dim3(128), dim3(256), 0, stream>>>(w, wpk);
    conv_mfma<<<dim3(512, 2), dim3(256), 0, stream>>>(xp, wpk, bias, out);
}